// Round 8
// baseline (30613.574 us; speedup 1.0000x reference)
//
#include <hip/hip_runtime.h>
#include <stdint.h>
#include <math.h>

#define TSTEPS 256
#define BATCH  256
#define OBS_D  512
#define FEATD  512
#define NACT   15
#define HDIM   528
#define HB     (HDIM*BATCH)   /* 135168 */
#define JT     8              /* j-values per LSTM tile (x4 gates = 32 rows) */
#define BT     64             /* batch per LSTM block */

/* ---- compact ws layout (same as R7, ~5.8 MB) ---- */
#define OFF_ND    0
#define OFF_FLAG  65536
#define ALW_BYTES 262208
#define SB        91952
#define FXT       (SB)
#define FH0       (FXT + 4*HB)
#define FH1       (FH0 + 2*HB)
#define FC0       (FH1 + 2*HB)
#define FC1       (FC0 + HB)

/* ALW float offsets */
#define DBS0   0
#define DBS1   2112
#define DBENC  4224
#define DHW    4736
#define DHB    13184
#define DALW_N 13200

/* out float offsets */
#define OUT_POL   0
#define OUT_BASE  983040
#define OUT_ACT   1048576
#define OUT_H     1114112
#define OUT_C     1384448

__device__ __forceinline__ float sigf_(float x){ return 1.0f/(1.0f+expf(-x)); }

__device__ __forceinline__ uint32_t rotl32_(uint32_t x, uint32_t d){
  return (x<<d)|(x>>(32u-d));
}

/* JAX partitionable threefry 32-bit: bits = out0 ^ out1. [VERIFIED R5-R7] */
__device__ double gumbel_for(uint32_t idx){
  uint32_t x0 = 0u, x1 = idx;
  const uint32_t k0 = 0u, k1 = 1u;
  const uint32_t ks[3] = {k0, k1, 0x1BD11BDAu ^ k0 ^ k1};
  x0 += ks[0]; x1 += ks[1];
  const uint32_t R0[4] = {13u,15u,26u,6u}, R1[4] = {17u,29u,16u,24u};
  #pragma unroll
  for (int g=0; g<5; ++g){
    const uint32_t* r = (g&1) ? R1 : R0;
    #pragma unroll
    for (int j=0;j<4;++j){ x0 += x1; x1 = rotl32_(x1, r[j]); x1 ^= x0; }
    x0 += ks[(g+1)%3];
    x1 += ks[(g+2)%3] + (uint32_t)(g+1);
  }
  const uint32_t bits = x0 ^ x1;
  float u = __uint_as_float((bits>>9) | 0x3f800000u) - 1.0f;
  const float TINY = 1.17549435e-38f;
  u = u * (1.0f - TINY) + TINY;
  u = fmaxf(TINY, u);
  return -log(-log((double)u));
}

__global__ void zero_kernel(float* __restrict__ p, int n){
  int i = blockIdx.x*256 + threadIdx.x;
  if (i < n) p[i] = 0.0f;
}

__global__ void detect_term_kernel(const void* __restrict__ term, int* __restrict__ flag){
  __shared__ int s_nf, s_nb, s_ni;
  if (threadIdx.x==0){ s_nf=0; s_nb=0; s_ni=0; }
  __syncthreads();
  const uint8_t*  pb = (const uint8_t*)term;
  const uint32_t* pw = (const uint32_t*)term;
  int nf=0, nb=0, ni=0;
  for (int i=threadIdx.x; i<16384; i+=256){
    uint32_t v = pw[i];
    if (v == 0x3F800000u) nf++;
    if (v == 1u) ni++;
  }
  for (int o=threadIdx.x; o<65536; o+=256){
    if ((o&3) && pb[o]) nb++;
  }
  if (nf) atomicAdd(&s_nf, nf);
  if (nb) atomicAdd(&s_nb, nb);
  if (ni) atomicAdd(&s_ni, ni);
  __syncthreads();
  if (threadIdx.x==0){
    flag[0] = (s_nf>0) ? 2 : ((s_nb>0) ? 0 : ((s_ni>0) ? 1 : 0));
  }
}

__global__ void nd_kernel(const void* __restrict__ term, const int* __restrict__ flag,
                          float* __restrict__ nd){
  int i = blockIdx.x*256 + threadIdx.x;
  if (i >= TSTEPS*BATCH) return;
  int f = flag[0];
  bool done;
  if (f == 0)      done = ((const uint8_t*)term)[i] != 0;
  else if (f == 1) done = ((const int*)term)[i] != 0;
  else             done = ((const float*)term)[i] != 0.0f;
  nd[i] = done ? 0.0f : 1.0f;
}

__global__ void prep_small_kernel(float* __restrict__ alw,
    const float* __restrict__ bih0, const float* __restrict__ bhh0,
    const float* __restrict__ bih1, const float* __restrict__ bhh1,
    const float* __restrict__ benc,
    const float* __restrict__ Wpol, const float* __restrict__ bpol,
    const float* __restrict__ Wbase, const float* __restrict__ bbase){
  int i = blockIdx.x*256 + threadIdx.x;
  if (i >= DALW_N) return;
  if (i < 2112)            alw[DBS0 + i] = bih0[i] + bhh0[i];
  else if (i < 4224)       { int j=i-2112; alw[DBS1 + j] = bih1[j] + bhh1[j]; }
  else if (i < 4736)       { int j=i-4224; alw[DBENC + j] = benc[j]; }
  else if (i < 13184)      { int j=i-4736; int r=j/HDIM, k=j%HDIM;
                             alw[DHW + j] = (r<NACT ? Wpol[r*HDIM+k] : Wbase[k]); }
  else                     { int j=i-13184; alw[DHB + j] = (j<NACT ? bpol[j] : bbase[0]); }
}

/* LSTM tile: 8 j x 4 gates x 64 batch. Weight slab double-buffered in LDS.
   Accumulation order bitwise-identical to R7 (bias -> x-dot -> masked h-dot). */
__device__ __forceinline__ void lstm32(
    float* __restrict__ smem,          /* 2 x 32 x 132 floats */
    int tile, int bq, int step,
    const float* __restrict__ srcA, const float* __restrict__ srcB,
    const float* __restrict__ wih, const float* __restrict__ whh,
    const float* __restrict__ bsum, const float* __restrict__ nd,
    float* __restrict__ cbuf, float* __restrict__ hout)
{
  const int t = threadIdx.x;
  const int p    = t & 31;        /* batch pair within 64-batch tile */
  const int colg = t >> 5;        /* 0..7 -> j offset */
  const int j0 = tile * JT;
  const int b0 = bq * BT + 2*p;
  const float nd0 = nd[step*BATCH + b0];
  const float nd1 = nd[step*BATCH + b0 + 1];

  /* staging mapping: thread stages slab row rr = gate*8 + jj */
  const int rr  = t >> 3;                       /* 0..31 */
  const int sg  = rr >> 3;                      /* gate */
  const int sj  = rr & 7;                       /* j offset */
  const int kk0 = (t & 7) * 16;                 /* 128-chunk: 16 floats each */
  const int kk0r= (t & 7) * 2;                  /* 16-rem chunk: 2 floats each */
  const size_t srow = (size_t)(sg*HDIM + j0 + sj) * HDIM;

  float acc[4][2];
  #pragma unroll
  for (int g=0; g<4; ++g){
    const float bv = bsum[g*HDIM + j0 + colg];
    acc[g][0] = bv; acc[g][1] = bv;
  }

  float4 s4[4]; float2 s2;

  /* prologue: stage chunk 0 (wih, kc=0) into buf 0 */
  {
    const float* wp = wih + srow;
    #pragma unroll
    for (int u=0; u<4; ++u) s4[u] = *(const float4*)(wp + kk0 + u*4);
    #pragma unroll
    for (int u=0; u<4; ++u) *(float4*)(smem + rr*132 + kk0 + u*4) = s4[u];
  }
  __syncthreads();

  #pragma unroll 1
  for (int cc=0; cc<10; ++cc){
    const int pass = cc / 5;          /* 0: wih/x, 1: whh/h */
    const int ch   = cc % 5;
    const int kc   = ch * 128;
    const int klen = (ch==4) ? 16 : 128;
    const int buf  = cc & 1;

    /* prefetch next chunk's weights into regs (latency hidden by compute) */
    const bool havenext = (cc+1) < 10;
    if (havenext){
      const int npass = (cc+1)/5, nch = (cc+1)%5;
      const float* wp = (npass ? whh : wih) + srow + nch*128;
      if (nch < 4){
        #pragma unroll
        for (int u=0; u<4; ++u) s4[u] = *(const float4*)(wp + kk0 + u*4);
      } else {
        s2 = *(const float2*)(wp + kk0r);
      }
    }

    /* compute this chunk */
    const float* asrc = (pass==0) ? srcA : srcB;
    const float* lbase = smem + buf*4224;
    #pragma unroll 2
    for (int kk=0; kk<klen; kk+=4){
      float4 wv[4];
      #pragma unroll
      for (int g=0; g<4; ++g)
        wv[g] = *(const float4*)(lbase + (g*8+colg)*132 + kk);
      const float* ap = asrc + (size_t)(kc+kk)*BATCH + b0;
      #pragma unroll
      for (int q=0; q<4; ++q){
        float2 av = *(const float2*)(ap + (size_t)q*BATCH);
        if (pass==1){ av.x *= nd0; av.y *= nd1; }
        #pragma unroll
        for (int g=0; g<4; ++g){
          const float wq = ((const float*)&wv[g])[q];
          acc[g][0] = fmaf(wq, av.x, acc[g][0]);
          acc[g][1] = fmaf(wq, av.y, acc[g][1]);
        }
      }
    }

    /* write prefetched chunk into the other buffer (readers done last iter) */
    if (havenext){
      const int nbuf = (cc+1)&1, nch = (cc+1)%5;
      float* wb = smem + nbuf*4224 + rr*132;
      if (nch < 4){
        #pragma unroll
        for (int u=0; u<4; ++u) *(float4*)(wb + kk0 + u*4) = s4[u];
      } else {
        *(float2*)(wb + kk0r) = s2;
      }
    }
    __syncthreads();
  }

  /* epilogue: gates i,f,g,o -> c,h for j = j0+colg, batch b0,b0+1 */
  const int j = j0 + colg;
  const int idx = j*BATCH + b0;
  #pragma unroll
  for (int u=0; u<2; ++u){
    const float ndv = u ? nd1 : nd0;
    const float cold = cbuf[idx+u] * ndv;
    const float cn = sigf_(acc[1][u])*cold + sigf_(acc[0][u])*tanhf(acc[2][u]);
    const float hn = sigf_(acc[3][u])*tanhf(cn);
    cbuf[idx+u] = cn; hout[idx+u] = hn;
  }
}

/* Skewed pipeline: [0,264)=L0@t, [264,528)=L1@t-1, [528,592)=enc@t+2,
   592=enc extras @t+2, 593=head+sample @t-2.
   LSTM block id r: tile = r>>2 (66 tiles), bq = r&3 (batch quarter). */
__global__ __launch_bounds__(256) void step_kernel(
  const float* __restrict__ obs, const int* __restrict__ lastAct,
  const float* __restrict__ reward,
  const float* __restrict__ wenc,
  const float* __restrict__ wih0, const float* __restrict__ whh0,
  const float* __restrict__ wih1, const float* __restrict__ whh1,
  float* __restrict__ ws, float* __restrict__ alw,
  float* __restrict__ out, int t)
{
  __shared__ float smem[8448];   /* LSTM: 2x32x132; enc: 32x257 (8224) */
  const int bid = blockIdx.x;
  const int b = threadIdx.x;
  float* nd = ws + OFF_ND;
  float* xT = ws + FXT;
  float* h0 = ws + FH0;
  float* h1 = ws + FH1;
  float* c0 = ws + FC0;
  float* c1 = ws + FC1;

  if (bid < 264) {                       /* layer 0 @ t */
    if (t < 0 || t > 255) return;
    lstm32(smem, bid>>2, bid&3, t,
           xT + (size_t)(t&3)*HB,
           h0 + (size_t)((t+1)&1)*HB,
           wih0, whh0, alw + DBS0, nd, c0,
           h0 + (size_t)(t&1)*HB);
  } else if (bid < 528) {                /* layer 1 @ t-1 */
    const int s = t - 1;
    if (s < 0 || s > 255) return;
    const int r = bid - 264;
    lstm32(smem, r>>2, r&3, s,
           h0 + (size_t)(s&1)*HB,
           h1 + (size_t)((s+1)&1)*HB,
           wih1, whh1, alw + DBS1, nd, c1,
           h1 + (size_t)(s&1)*HB);
  } else if (bid < 593) {                /* encoder @ t+2 */
    const int te = t + 2;
    if (te < 0 || te > 255) return;
    float* xs = xT + (size_t)(te&3)*HB;
    if (bid < 592) {
      const int e = bid - 528;
      const int f0 = e*8;
      float acc[8];
      const float* wrow[8];
      #pragma unroll
      for (int c=0;c<8;++c){ acc[c]=alw[DBENC+f0+c]; wrow[c]=wenc+(size_t)(f0+c)*OBS_D; }
      const int r0 = threadIdx.x>>3;
      const int kk = (threadIdx.x&7)<<2;
      for (int kc=0; kc<OBS_D; kc+=32){
        __syncthreads();
        #pragma unroll
        for (int rr=0; rr<256; rr+=32){
          const float4 v = *(const float4*)(obs + ((size_t)te*BATCH + (r0+rr))*OBS_D + kc + kk);
          smem[(kk+0)*257 + r0+rr]=v.x; smem[(kk+1)*257 + r0+rr]=v.y;
          smem[(kk+2)*257 + r0+rr]=v.z; smem[(kk+3)*257 + r0+rr]=v.w;
        }
        __syncthreads();
        #pragma unroll 4
        for (int k2=0;k2<32;++k2){
          const float xv = smem[k2*257 + b];
          #pragma unroll
          for (int c=0;c<8;++c) acc[c] = fmaf(xv, wrow[c][kc+k2], acc[c]);
        }
      }
      #pragma unroll
      for (int c=0;c<8;++c) xs[(size_t)(f0+c)*BATCH + b] = fmaxf(acc[c], 0.0f);
    } else {
      const float r = reward[te*BATCH + b];
      xs[(size_t)FEATD*BATCH + b] = fminf(fmaxf(r, -1.0f), 1.0f);
      const int la = lastAct[te*BATCH + b];
      #pragma unroll
      for (int a2=0; a2<NACT; ++a2)
        xs[(size_t)(FEATD+1+a2)*BATCH + b] = (a2==la) ? 1.0f : 0.0f;
    }
  } else {                               /* head + sampling @ t-2 */
    const int s = t - 2;
    if (s < 0 || s > 255) return;
    const float* hsrc = h1 + (size_t)(s&1)*HB;
    float acc[16];
    #pragma unroll
    for (int c=0;c<16;++c) acc[c]=alw[DHB+c];
    const float* hb = hsrc + b;
    #pragma unroll 4
    for (int k=0;k<HDIM;++k){
      const float hv = hb[(size_t)k*BATCH];
      #pragma unroll
      for (int c=0;c<16;++c) acc[c] = fmaf(hv, alw[DHW + (size_t)c*HDIM + k], acc[c]);
    }
    const int row = s*BATCH + b;
    #pragma unroll
    for (int c=0;c<15;++c) out[OUT_POL + (size_t)row*NACT + c] = acc[c];
    out[OUT_BASE + row] = acc[15];
    double best = -1.0e300; int bi = 0;
    #pragma unroll
    for (int a2=0; a2<NACT; ++a2){
      const double v = (double)acc[a2] + gumbel_for((uint32_t)(row*NACT + a2));
      if (v > best){ best = v; bi = a2; }
    }
    out[OUT_ACT + row] = (float)bi;
  }
}

__global__ void finalize_kernel(const float* __restrict__ ws, float* __restrict__ out){
  int i = blockIdx.x*256 + threadIdx.x;
  if (i >= 2*HB) return;
  const int l = i / HB;
  const int r = i % HB;
  const int bq = r / HDIM;
  const int j  = r % HDIM;
  const float* hf = ws + (l==0 ? FH0 : FH1) + HB;   /* step-255 parity = 1 */
  const float* cf = ws + (l==0 ? FC0 : FC1);
  out[OUT_H + i] = hf[(size_t)j*BATCH + bq];
  out[OUT_C + i] = cf[(size_t)j*BATCH + bq];
}

extern "C" void kernel_launch(void* const* d_in, const int* in_sizes, int n_in,
                              void* d_out, int out_size, void* d_ws, size_t ws_size,
                              hipStream_t stream) {
  const float* obs     = (const float*)d_in[0];
  const int*   lastAct = (const int*)  d_in[1];
  const float* reward  = (const float*)d_in[2];
  const void*  term    =               d_in[3];
  const float* Wenc    = (const float*)d_in[4];
  const float* benc    = (const float*)d_in[5];
  const float* wih0    = (const float*)d_in[6];
  const float* whh0    = (const float*)d_in[7];
  const float* bih0    = (const float*)d_in[8];
  const float* bhh0    = (const float*)d_in[9];
  const float* wih1    = (const float*)d_in[10];
  const float* whh1    = (const float*)d_in[11];
  const float* bih1    = (const float*)d_in[12];
  const float* bhh1    = (const float*)d_in[13];
  const float* Wpol    = (const float*)d_in[14];
  const float* bpol    = (const float*)d_in[15];
  const float* Wbase   = (const float*)d_in[16];
  const float* bbase   = (const float*)d_in[17];
  float*  ws   = (float*)d_ws;
  int*    flag = (int*)(ws + OFF_FLAG);
  float*  alw  = (float*)((char*)d_ws + ALW_BYTES);
  float*  out  = (float*)d_out;

  /* zero h/c state (6*HB floats at FH0) every call */
  {
    const int nz = 6*HB;
    zero_kernel<<<(nz+255)/256, 256, 0, stream>>>(ws + FH0, nz);
  }
  detect_term_kernel<<<1, 256, 0, stream>>>(term, flag);
  nd_kernel<<<(TSTEPS*BATCH+255)/256, 256, 0, stream>>>(term, flag, ws + OFF_ND);
  prep_small_kernel<<<(DALW_N+255)/256, 256, 0, stream>>>(alw,
      bih0, bhh0, bih1, bhh1, benc, Wpol, bpol, Wbase, bbase);

  for (int t = -2; t <= 257; ++t) {
    step_kernel<<<594, 256, 0, stream>>>(
      obs, lastAct, reward,
      Wenc, wih0, whh0, wih1, whh1,
      ws, alw, out, t);
  }
  finalize_kernel<<<(2*HB+255)/256, 256, 0, stream>>>(ws, out);
}

// Round 9
// 29569.440 us; speedup vs baseline: 1.0353x; 1.0353x over previous
//
#include <hip/hip_runtime.h>
#include <stdint.h>
#include <math.h>

#define TSTEPS 256
#define BATCH  256
#define OBS_D  512
#define FEATD  512
#define NACT   15
#define HDIM   528
#define HB     (HDIM*BATCH)   /* 135168 */

/* ---- compact ws layout (same as R7, ~5.8 MB) ---- */
#define OFF_ND    0
#define OFF_FLAG  65536
#define ALW_BYTES 262208
#define SB        91952
#define FXT       (SB)
#define FH0       (FXT + 4*HB)
#define FH1       (FH0 + 2*HB)
#define FC0       (FH1 + 2*HB)
#define FC1       (FC0 + HB)

/* ALW float offsets */
#define DBS0   0
#define DBS1   2112
#define DBENC  4224
#define DHW    4736
#define DHB    13184
#define DALW_N 13200

/* out float offsets */
#define OUT_POL   0
#define OUT_BASE  983040
#define OUT_ACT   1048576
#define OUT_H     1114112
#define OUT_C     1384448

__device__ __forceinline__ float sigf_(float x){ return 1.0f/(1.0f+expf(-x)); }

__device__ __forceinline__ uint32_t rotl32_(uint32_t x, uint32_t d){
  return (x<<d)|(x>>(32u-d));
}

/* JAX partitionable threefry 32-bit: bits = out0 ^ out1. [VERIFIED R5-R8] */
__device__ double gumbel_for(uint32_t idx){
  uint32_t x0 = 0u, x1 = idx;
  const uint32_t k0 = 0u, k1 = 1u;
  const uint32_t ks[3] = {k0, k1, 0x1BD11BDAu ^ k0 ^ k1};
  x0 += ks[0]; x1 += ks[1];
  const uint32_t R0[4] = {13u,15u,26u,6u}, R1[4] = {17u,29u,16u,24u};
  #pragma unroll
  for (int g=0; g<5; ++g){
    const uint32_t* r = (g&1) ? R1 : R0;
    #pragma unroll
    for (int j=0;j<4;++j){ x0 += x1; x1 = rotl32_(x1, r[j]); x1 ^= x0; }
    x0 += ks[(g+1)%3];
    x1 += ks[(g+2)%3] + (uint32_t)(g+1);
  }
  const uint32_t bits = x0 ^ x1;
  float u = __uint_as_float((bits>>9) | 0x3f800000u) - 1.0f;
  const float TINY = 1.17549435e-38f;
  u = u * (1.0f - TINY) + TINY;
  u = fmaxf(TINY, u);
  return -log(-log((double)u));
}

__global__ void zero_kernel(float* __restrict__ p, int n){
  int i = blockIdx.x*256 + threadIdx.x;
  if (i < n) p[i] = 0.0f;
}

__global__ void detect_term_kernel(const void* __restrict__ term, int* __restrict__ flag){
  __shared__ int s_nf, s_nb, s_ni;
  if (threadIdx.x==0){ s_nf=0; s_nb=0; s_ni=0; }
  __syncthreads();
  const uint8_t*  pb = (const uint8_t*)term;
  const uint32_t* pw = (const uint32_t*)term;
  int nf=0, nb=0, ni=0;
  for (int i=threadIdx.x; i<16384; i+=256){
    uint32_t v = pw[i];
    if (v == 0x3F800000u) nf++;
    if (v == 1u) ni++;
  }
  for (int o=threadIdx.x; o<65536; o+=256){
    if ((o&3) && pb[o]) nb++;
  }
  if (nf) atomicAdd(&s_nf, nf);
  if (nb) atomicAdd(&s_nb, nb);
  if (ni) atomicAdd(&s_ni, ni);
  __syncthreads();
  if (threadIdx.x==0){
    flag[0] = (s_nf>0) ? 2 : ((s_nb>0) ? 0 : ((s_ni>0) ? 1 : 0));
  }
}

__global__ void nd_kernel(const void* __restrict__ term, const int* __restrict__ flag,
                          float* __restrict__ nd){
  int i = blockIdx.x*256 + threadIdx.x;
  if (i >= TSTEPS*BATCH) return;
  int f = flag[0];
  bool done;
  if (f == 0)      done = ((const uint8_t*)term)[i] != 0;
  else if (f == 1) done = ((const int*)term)[i] != 0;
  else             done = ((const float*)term)[i] != 0.0f;
  nd[i] = done ? 0.0f : 1.0f;
}

__global__ void prep_small_kernel(float* __restrict__ alw,
    const float* __restrict__ bih0, const float* __restrict__ bhh0,
    const float* __restrict__ bih1, const float* __restrict__ bhh1,
    const float* __restrict__ benc,
    const float* __restrict__ Wpol, const float* __restrict__ bpol,
    const float* __restrict__ Wbase, const float* __restrict__ bbase){
  int i = blockIdx.x*256 + threadIdx.x;
  if (i >= DALW_N) return;
  if (i < 2112)            alw[DBS0 + i] = bih0[i] + bhh0[i];
  else if (i < 4224)       { int j=i-2112; alw[DBS1 + j] = bih1[j] + bhh1[j]; }
  else if (i < 4736)       { int j=i-4224; alw[DBENC + j] = benc[j]; }
  else if (i < 13184)      { int j=i-4736; int r=j/HDIM, k=j%HDIM;
                             alw[DHW + j] = (r<NACT ? Wpol[r*HDIM+k] : Wbase[k]); }
  else                     { int j=i-13184; alw[DHB + j] = (j<NACT ? bpol[j] : bbase[0]); }
}

/* One LSTM layer j-tile (8 gate cols), thread = batch row. Pure f32.
   Software-pipelined activation loads: prefetch group g+1 (8 loads) into a
   second register set while FMA-ing group g -> L2 latency hidden behind
   64 FMAs x 2+ waves/SIMD. FMA order identical to R7 (k ascending, c inner). */
__device__ __forceinline__ void lstm_block(
    int jt, int step, const float* __restrict__ srcA, const float* __restrict__ srcB,
    const float* __restrict__ wih, const float* __restrict__ whh,
    const float* __restrict__ bsum,
    const float* __restrict__ nd, float* __restrict__ cbuf, float* __restrict__ hout,
    int b)
{
  const int j0 = jt*2;
  const float ndv = nd[step*BATCH + b];
  float acc[8];
  const float* wA[8]; const float* wB[8];
  #pragma unroll
  for (int c=0;c<8;++c){
    const int col = (c>>1)*HDIM + j0 + (c&1);
    acc[c] = bsum[col];
    wA[c] = wih + (size_t)col*HDIM;
    wB[c] = whh + (size_t)col*HDIM;
  }

  /* ---- pass 1: x-dot, k = 0..527, pipelined in groups of 8 ---- */
  {
    const float* a = srcA + b;
    float xc[8], xn[8];
    #pragma unroll
    for (int u=0;u<8;++u) xc[u] = a[(size_t)u*BATCH];
    #pragma unroll 1
    for (int g=0; g<66; ++g){
      if (g < 65){
        const float* ap = a + (size_t)(g+1)*8*BATCH;
        #pragma unroll
        for (int u=0;u<8;++u) xn[u] = ap[(size_t)u*BATCH];
      }
      const int kb = g*8;
      #pragma unroll
      for (int u=0;u<8;++u){
        const float xv = xc[u];
        #pragma unroll
        for (int c=0;c<8;++c) acc[c] = fmaf(wA[c][kb+u], xv, acc[c]);
      }
      #pragma unroll
      for (int u=0;u<8;++u) xc[u] = xn[u];
    }
  }

  /* ---- pass 2: masked h-dot, k = 0..527, pipelined ---- */
  {
    const float* bb = srcB + b;
    float xc[8], xn[8];
    #pragma unroll
    for (int u=0;u<8;++u) xc[u] = bb[(size_t)u*BATCH];
    #pragma unroll 1
    for (int g=0; g<66; ++g){
      if (g < 65){
        const float* ap = bb + (size_t)(g+1)*8*BATCH;
        #pragma unroll
        for (int u=0;u<8;++u) xn[u] = ap[(size_t)u*BATCH];
      }
      const int kb = g*8;
      #pragma unroll
      for (int u=0;u<8;++u){
        const float hv = xc[u] * ndv;
        #pragma unroll
        for (int c=0;c<8;++c) acc[c] = fmaf(wB[c][kb+u], hv, acc[c]);
      }
      #pragma unroll
      for (int u=0;u<8;++u) xc[u] = xn[u];
    }
  }

  #pragma unroll
  for (int jj=0;jj<2;++jj){
    const float gi=acc[0+jj], gf=acc[2+jj], gg=acc[4+jj], go=acc[6+jj];
    const int idx=(j0+jj)*BATCH+b;
    const float cold = cbuf[idx]*ndv;
    const float cn = sigf_(gf)*cold + sigf_(gi)*tanhf(gg);
    const float hn = sigf_(go)*tanhf(cn);
    cbuf[idx]=cn; hout[idx]=hn;
  }
}

/* Skewed pipeline: [0,264)=L0@t, [264,528)=L1@t-1, [528,592)=enc@t+2,
   592=enc extras @t+2, 593=head+sample @t-2 */
__global__ __launch_bounds__(256, 2) void step_kernel(
  const float* __restrict__ obs, const int* __restrict__ lastAct,
  const float* __restrict__ reward,
  const float* __restrict__ wenc,
  const float* __restrict__ wih0, const float* __restrict__ whh0,
  const float* __restrict__ wih1, const float* __restrict__ whh1,
  float* __restrict__ ws, float* __restrict__ alw,
  float* __restrict__ out, int t)
{
  const int bid = blockIdx.x;
  const int b = threadIdx.x;
  float* nd = ws + OFF_ND;
  float* xT = ws + FXT;
  float* h0 = ws + FH0;
  float* h1 = ws + FH1;
  float* c0 = ws + FC0;
  float* c1 = ws + FC1;

  if (bid < 264) {                       /* layer 0 @ t */
    if (t < 0 || t > 255) return;
    lstm_block(bid, t,
               xT + (size_t)(t&3)*HB,
               h0 + (size_t)((t+1)&1)*HB,
               wih0, whh0, alw + DBS0, nd, c0,
               h0 + (size_t)(t&1)*HB, b);
  } else if (bid < 528) {                /* layer 1 @ t-1 */
    const int s = t - 1;
    if (s < 0 || s > 255) return;
    lstm_block(bid-264, s,
               h0 + (size_t)(s&1)*HB,
               h1 + (size_t)((s+1)&1)*HB,
               wih1, whh1, alw + DBS1, nd, c1,
               h1 + (size_t)(s&1)*HB, b);
  } else if (bid < 593) {                /* encoder @ t+2 */
    const int te = t + 2;
    if (te < 0 || te > 255) return;
    float* xs = xT + (size_t)(te&3)*HB;
    if (bid < 592) {
      const int e = bid - 528;
      const int f0 = e*8;
      float acc[8];
      const float* wrow[8];
      #pragma unroll
      for (int c=0;c<8;++c){ acc[c]=alw[DBENC+f0+c]; wrow[c]=wenc+(size_t)(f0+c)*OBS_D; }
      __shared__ float lx[32][257];
      const int r0 = threadIdx.x>>3;
      const int kk = (threadIdx.x&7)<<2;
      for (int kc=0; kc<OBS_D; kc+=32){
        __syncthreads();
        #pragma unroll
        for (int rr=0; rr<256; rr+=32){
          const float4 v = *(const float4*)(obs + ((size_t)te*BATCH + (r0+rr))*OBS_D + kc + kk);
          lx[kk+0][r0+rr]=v.x; lx[kk+1][r0+rr]=v.y; lx[kk+2][r0+rr]=v.z; lx[kk+3][r0+rr]=v.w;
        }
        __syncthreads();
        #pragma unroll 4
        for (int k2=0;k2<32;++k2){
          const float xv = lx[k2][b];
          #pragma unroll
          for (int c=0;c<8;++c) acc[c] = fmaf(xv, wrow[c][kc+k2], acc[c]);
        }
      }
      #pragma unroll
      for (int c=0;c<8;++c) xs[(size_t)(f0+c)*BATCH + b] = fmaxf(acc[c], 0.0f);
    } else {
      const float r = reward[te*BATCH + b];
      xs[(size_t)FEATD*BATCH + b] = fminf(fmaxf(r, -1.0f), 1.0f);
      const int la = lastAct[te*BATCH + b];
      #pragma unroll
      for (int a2=0; a2<NACT; ++a2)
        xs[(size_t)(FEATD+1+a2)*BATCH + b] = (a2==la) ? 1.0f : 0.0f;
    }
  } else {                               /* head + sampling @ t-2 */
    const int s = t - 2;
    if (s < 0 || s > 255) return;
    const float* hsrc = h1 + (size_t)(s&1)*HB;
    float acc[16];
    #pragma unroll
    for (int c=0;c<16;++c) acc[c]=alw[DHB+c];
    const float* hb = hsrc + b;
    #pragma unroll 4
    for (int k=0;k<HDIM;++k){
      const float hv = hb[(size_t)k*BATCH];
      #pragma unroll
      for (int c=0;c<16;++c) acc[c] = fmaf(hv, alw[DHW + (size_t)c*HDIM + k], acc[c]);
    }
    const int row = s*BATCH + b;
    #pragma unroll
    for (int c=0;c<15;++c) out[OUT_POL + (size_t)row*NACT + c] = acc[c];
    out[OUT_BASE + row] = acc[15];
    double best = -1.0e300; int bi = 0;
    #pragma unroll
    for (int a2=0; a2<NACT; ++a2){
      const double v = (double)acc[a2] + gumbel_for((uint32_t)(row*NACT + a2));
      if (v > best){ best = v; bi = a2; }
    }
    out[OUT_ACT + row] = (float)bi;
  }
}

__global__ void finalize_kernel(const float* __restrict__ ws, float* __restrict__ out){
  int i = blockIdx.x*256 + threadIdx.x;
  if (i >= 2*HB) return;
  const int l = i / HB;
  const int r = i % HB;
  const int bq = r / HDIM;
  const int j  = r % HDIM;
  const float* hf = ws + (l==0 ? FH0 : FH1) + HB;   /* step-255 parity = 1 */
  const float* cf = ws + (l==0 ? FC0 : FC1);
  out[OUT_H + i] = hf[(size_t)j*BATCH + bq];
  out[OUT_C + i] = cf[(size_t)j*BATCH + bq];
}

extern "C" void kernel_launch(void* const* d_in, const int* in_sizes, int n_in,
                              void* d_out, int out_size, void* d_ws, size_t ws_size,
                              hipStream_t stream) {
  const float* obs     = (const float*)d_in[0];
  const int*   lastAct = (const int*)  d_in[1];
  const float* reward  = (const float*)d_in[2];
  const void*  term    =               d_in[3];
  const float* Wenc    = (const float*)d_in[4];
  const float* benc    = (const float*)d_in[5];
  const float* wih0    = (const float*)d_in[6];
  const float* whh0    = (const float*)d_in[7];
  const float* bih0    = (const float*)d_in[8];
  const float* bhh0    = (const float*)d_in[9];
  const float* wih1    = (const float*)d_in[10];
  const float* whh1    = (const float*)d_in[11];
  const float* bih1    = (const float*)d_in[12];
  const float* bhh1    = (const float*)d_in[13];
  const float* Wpol    = (const float*)d_in[14];
  const float* bpol    = (const float*)d_in[15];
  const float* Wbase   = (const float*)d_in[16];
  const float* bbase   = (const float*)d_in[17];
  float*  ws   = (float*)d_ws;
  int*    flag = (int*)(ws + OFF_FLAG);
  float*  alw  = (float*)((char*)d_ws + ALW_BYTES);
  float*  out  = (float*)d_out;

  /* zero h/c state (6*HB floats at FH0) every call */
  {
    const int nz = 6*HB;
    zero_kernel<<<(nz+255)/256, 256, 0, stream>>>(ws + FH0, nz);
  }
  detect_term_kernel<<<1, 256, 0, stream>>>(term, flag);
  nd_kernel<<<(TSTEPS*BATCH+255)/256, 256, 0, stream>>>(term, flag, ws + OFF_ND);
  prep_small_kernel<<<(DALW_N+255)/256, 256, 0, stream>>>(alw,
      bih0, bhh0, bih1, bhh1, benc, Wpol, bpol, Wbase, bbase);

  for (int t = -2; t <= 257; ++t) {
    step_kernel<<<594, 256, 0, stream>>>(
      obs, lastAct, reward,
      Wenc, wih0, whh0, wih1, whh1,
      ws, alw, out, t);
  }
  finalize_kernel<<<(2*HB+255)/256, 256, 0, stream>>>(ws, out);
}

// Round 10
// 29309.552 us; speedup vs baseline: 1.0445x; 1.0089x over previous
//
#include <hip/hip_runtime.h>
#include <stdint.h>
#include <math.h>

#define TSTEPS 256
#define BATCH  256
#define OBS_D  512
#define FEATD  512
#define NACT   15
#define HDIM   528
#define HB     (HDIM*BATCH)   /* 135168 */

/* ---- compact ws layout (~5.8 MB). Activations (x,h,c) are k-packed:
   p[(k>>2)*(BATCH*4) + b*4 + (k&3)]  — float4 per (4k, b). ---- */
#define OFF_ND    0
#define OFF_FLAG  65536
#define ALW_BYTES 262208
#define SB        91952
#define FXT       (SB)
#define FH0       (FXT + 4*HB)
#define FH1       (FH0 + 2*HB)
#define FC0       (FH1 + 2*HB)
#define FC1       (FC0 + HB)

/* ALW float offsets */
#define DBS0   0
#define DBS1   2112
#define DBENC  4224
#define DHW    4736
#define DHB    13184
#define DALW_N 13200

/* out float offsets */
#define OUT_POL   0
#define OUT_BASE  983040
#define OUT_ACT   1048576
#define OUT_H     1114112
#define OUT_C     1384448

__device__ __forceinline__ float sigf_(float x){ return 1.0f/(1.0f+expf(-x)); }

__device__ __forceinline__ uint32_t rotl32_(uint32_t x, uint32_t d){
  return (x<<d)|(x>>(32u-d));
}

/* JAX partitionable threefry 32-bit: bits = out0 ^ out1. [VERIFIED R5-R9] */
__device__ double gumbel_for(uint32_t idx){
  uint32_t x0 = 0u, x1 = idx;
  const uint32_t k0 = 0u, k1 = 1u;
  const uint32_t ks[3] = {k0, k1, 0x1BD11BDAu ^ k0 ^ k1};
  x0 += ks[0]; x1 += ks[1];
  const uint32_t R0[4] = {13u,15u,26u,6u}, R1[4] = {17u,29u,16u,24u};
  #pragma unroll
  for (int g=0; g<5; ++g){
    const uint32_t* r = (g&1) ? R1 : R0;
    #pragma unroll
    for (int j=0;j<4;++j){ x0 += x1; x1 = rotl32_(x1, r[j]); x1 ^= x0; }
    x0 += ks[(g+1)%3];
    x1 += ks[(g+2)%3] + (uint32_t)(g+1);
  }
  const uint32_t bits = x0 ^ x1;
  float u = __uint_as_float((bits>>9) | 0x3f800000u) - 1.0f;
  const float TINY = 1.17549435e-38f;
  u = u * (1.0f - TINY) + TINY;
  u = fmaxf(TINY, u);
  return -log(-log((double)u));
}

__global__ void zero_kernel(float* __restrict__ p, int n){
  int i = blockIdx.x*256 + threadIdx.x;
  if (i < n) p[i] = 0.0f;
}

__global__ void detect_term_kernel(const void* __restrict__ term, int* __restrict__ flag){
  __shared__ int s_nf, s_nb, s_ni;
  if (threadIdx.x==0){ s_nf=0; s_nb=0; s_ni=0; }
  __syncthreads();
  const uint8_t*  pb = (const uint8_t*)term;
  const uint32_t* pw = (const uint32_t*)term;
  int nf=0, nb=0, ni=0;
  for (int i=threadIdx.x; i<16384; i+=256){
    uint32_t v = pw[i];
    if (v == 0x3F800000u) nf++;
    if (v == 1u) ni++;
  }
  for (int o=threadIdx.x; o<65536; o+=256){
    if ((o&3) && pb[o]) nb++;
  }
  if (nf) atomicAdd(&s_nf, nf);
  if (nb) atomicAdd(&s_nb, nb);
  if (ni) atomicAdd(&s_ni, ni);
  __syncthreads();
  if (threadIdx.x==0){
    flag[0] = (s_nf>0) ? 2 : ((s_nb>0) ? 0 : ((s_ni>0) ? 1 : 0));
  }
}

__global__ void nd_kernel(const void* __restrict__ term, const int* __restrict__ flag,
                          float* __restrict__ nd){
  int i = blockIdx.x*256 + threadIdx.x;
  if (i >= TSTEPS*BATCH) return;
  int f = flag[0];
  bool done;
  if (f == 0)      done = ((const uint8_t*)term)[i] != 0;
  else if (f == 1) done = ((const int*)term)[i] != 0;
  else             done = ((const float*)term)[i] != 0.0f;
  nd[i] = done ? 0.0f : 1.0f;
}

__global__ void prep_small_kernel(float* __restrict__ alw,
    const float* __restrict__ bih0, const float* __restrict__ bhh0,
    const float* __restrict__ bih1, const float* __restrict__ bhh1,
    const float* __restrict__ benc,
    const float* __restrict__ Wpol, const float* __restrict__ bpol,
    const float* __restrict__ Wbase, const float* __restrict__ bbase){
  int i = blockIdx.x*256 + threadIdx.x;
  if (i >= DALW_N) return;
  if (i < 2112)            alw[DBS0 + i] = bih0[i] + bhh0[i];
  else if (i < 4224)       { int j=i-2112; alw[DBS1 + j] = bih1[j] + bhh1[j]; }
  else if (i < 4736)       { int j=i-4224; alw[DBENC + j] = benc[j]; }
  else if (i < 13184)      { int j=i-4736; int r=j/HDIM, k=j%HDIM;
                             alw[DHW + j] = (r<NACT ? Wpol[r*HDIM+k] : Wbase[k]); }
  else                     { int j=i-13184; alw[DHB + j] = (j<NACT ? bpol[j] : bbase[0]); }
}

/* One LSTM layer j-tile (8 gate cols), thread = batch row. Pure f32.
   Acts k-packed: one float4 load covers 4 k (32 FMAs per load).
   FMA order identical to R7 (k ascending, c inner) -> bitwise-same results. */
__device__ __forceinline__ void lstm_block(
    int jt, int step, const float* __restrict__ srcA, const float* __restrict__ srcB,
    const float* __restrict__ wih, const float* __restrict__ whh,
    const float* __restrict__ bsum,
    const float* __restrict__ nd, float* __restrict__ cbuf, float* __restrict__ hout,
    int b)
{
  const int j0 = jt*2;
  const float ndv = nd[step*BATCH + b];
  float acc[8];
  const float* wA[8]; const float* wB[8];
  #pragma unroll
  for (int c=0;c<8;++c){
    const int col = (c>>1)*HDIM + j0 + (c&1);
    acc[c] = bsum[col];
    wA[c] = wih + (size_t)col*HDIM;
    wB[c] = whh + (size_t)col*HDIM;
  }

  /* pass 1: x-dot */
  {
    const float* ap = srcA + b*4;
    #pragma unroll 2
    for (int kq=0; kq<132; ++kq){
      const float4 av = *(const float4*)(ap + (size_t)kq*(BATCH*4));
      const int kb = kq*4;
      const float xv[4] = {av.x, av.y, av.z, av.w};
      #pragma unroll
      for (int u=0;u<4;++u){
        const float v = xv[u];
        #pragma unroll
        for (int c=0;c<8;++c) acc[c] = fmaf(wA[c][kb+u], v, acc[c]);
      }
    }
  }

  /* pass 2: masked h-dot */
  {
    const float* hp = srcB + b*4;
    #pragma unroll 2
    for (int kq=0; kq<132; ++kq){
      const float4 av = *(const float4*)(hp + (size_t)kq*(BATCH*4));
      const int kb = kq*4;
      const float xv[4] = {av.x, av.y, av.z, av.w};
      #pragma unroll
      for (int u=0;u<4;++u){
        const float v = xv[u] * ndv;
        #pragma unroll
        for (int c=0;c<8;++c) acc[c] = fmaf(wB[c][kb+u], v, acc[c]);
      }
    }
  }

  /* epilogue: gates i,f,g,o -> c,h at packed (j0, j0+1) */
  const int base = (j0>>2)*(BATCH*4) + b*4 + (j0&3);   /* (j0&3) in {0,2}, 8B aligned */
  float cv[2], hv[2];
  #pragma unroll
  for (int jj=0;jj<2;++jj){
    const float gi=acc[0+jj], gf=acc[2+jj], gg=acc[4+jj], go=acc[6+jj];
    const float cold = cbuf[base+jj]*ndv;
    const float cn = sigf_(gf)*cold + sigf_(gi)*tanhf(gg);
    const float hn = sigf_(go)*tanhf(cn);
    cv[jj]=cn; hv[jj]=hn;
  }
  *(float2*)(cbuf + base) = make_float2(cv[0], cv[1]);
  *(float2*)(hout + base) = make_float2(hv[0], hv[1]);
}

/* Skewed pipeline: [0,264)=L0@t, [264,528)=L1@t-1, [528,592)=enc@t+2,
   592=enc extras @t+2, 593=head+sample @t-2 */
__global__ __launch_bounds__(256) void step_kernel(
  const float* __restrict__ obs, const int* __restrict__ lastAct,
  const float* __restrict__ reward,
  const float* __restrict__ wenc,
  const float* __restrict__ wih0, const float* __restrict__ whh0,
  const float* __restrict__ wih1, const float* __restrict__ whh1,
  float* __restrict__ ws, float* __restrict__ alw,
  float* __restrict__ out, int t)
{
  const int bid = blockIdx.x;
  const int b = threadIdx.x;
  float* nd = ws + OFF_ND;
  float* xT = ws + FXT;
  float* h0 = ws + FH0;
  float* h1 = ws + FH1;
  float* c0 = ws + FC0;
  float* c1 = ws + FC1;

  if (bid < 264) {                       /* layer 0 @ t */
    if (t < 0 || t > 255) return;
    lstm_block(bid, t,
               xT + (size_t)(t&3)*HB,
               h0 + (size_t)((t+1)&1)*HB,
               wih0, whh0, alw + DBS0, nd, c0,
               h0 + (size_t)(t&1)*HB, b);
  } else if (bid < 528) {                /* layer 1 @ t-1 */
    const int s = t - 1;
    if (s < 0 || s > 255) return;
    lstm_block(bid-264, s,
               h0 + (size_t)(s&1)*HB,
               h1 + (size_t)((s+1)&1)*HB,
               wih1, whh1, alw + DBS1, nd, c1,
               h1 + (size_t)(s&1)*HB, b);
  } else if (bid < 593) {                /* encoder @ t+2 */
    const int te = t + 2;
    if (te < 0 || te > 255) return;
    float* xs = xT + (size_t)(te&3)*HB;
    if (bid < 592) {
      const int e = bid - 528;
      const int f0 = e*8;
      float acc[8];
      const float* wrow[8];
      #pragma unroll
      for (int c=0;c<8;++c){ acc[c]=alw[DBENC+f0+c]; wrow[c]=wenc+(size_t)(f0+c)*OBS_D; }
      __shared__ float lx[32][257];
      const int r0 = threadIdx.x>>3;
      const int kk = (threadIdx.x&7)<<2;
      for (int kc=0; kc<OBS_D; kc+=32){
        __syncthreads();
        #pragma unroll
        for (int rr=0; rr<256; rr+=32){
          const float4 v = *(const float4*)(obs + ((size_t)te*BATCH + (r0+rr))*OBS_D + kc + kk);
          lx[kk+0][r0+rr]=v.x; lx[kk+1][r0+rr]=v.y; lx[kk+2][r0+rr]=v.z; lx[kk+3][r0+rr]=v.w;
        }
        __syncthreads();
        #pragma unroll 4
        for (int k2=0;k2<32;++k2){
          const float xv = lx[k2][b];
          #pragma unroll
          for (int c=0;c<8;++c) acc[c] = fmaf(xv, wrow[c][kc+k2], acc[c]);
        }
      }
      /* packed write: features f0..f0+7 -> two float4 units */
      const float4 o0 = make_float4(fmaxf(acc[0],0.0f), fmaxf(acc[1],0.0f),
                                    fmaxf(acc[2],0.0f), fmaxf(acc[3],0.0f));
      const float4 o1 = make_float4(fmaxf(acc[4],0.0f), fmaxf(acc[5],0.0f),
                                    fmaxf(acc[6],0.0f), fmaxf(acc[7],0.0f));
      *(float4*)(xs + (size_t)(f0>>2)*(BATCH*4) + b*4)     = o0;
      *(float4*)(xs + (size_t)((f0>>2)+1)*(BATCH*4) + b*4) = o1;
    } else {
      /* extras: packed cols 512..527 = clipped reward + one-hot(15) */
      float vals[16];
      const float r = reward[te*BATCH + b];
      vals[0] = fminf(fmaxf(r, -1.0f), 1.0f);
      const int la = lastAct[te*BATCH + b];
      #pragma unroll
      for (int a2=0; a2<NACT; ++a2) vals[1+a2] = (a2==la) ? 1.0f : 0.0f;
      #pragma unroll
      for (int q=0; q<4; ++q){
        const float4 o = make_float4(vals[q*4], vals[q*4+1], vals[q*4+2], vals[q*4+3]);
        *(float4*)(xs + (size_t)(128+q)*(BATCH*4) + b*4) = o;
      }
    }
  } else {                               /* head + sampling @ t-2 */
    const int s = t - 2;
    if (s < 0 || s > 255) return;
    const float* hsrc = h1 + (size_t)(s&1)*HB;
    float acc[16];
    #pragma unroll
    for (int c=0;c<16;++c) acc[c]=alw[DHB+c];
    const float* hp = hsrc + b*4;
    #pragma unroll 2
    for (int kq=0; kq<132; ++kq){
      const float4 hv4 = *(const float4*)(hp + (size_t)kq*(BATCH*4));
      const int kb = kq*4;
      const float hvv[4] = {hv4.x, hv4.y, hv4.z, hv4.w};
      #pragma unroll
      for (int u=0;u<4;++u){
        const float hvu = hvv[u];
        #pragma unroll
        for (int c=0;c<16;++c) acc[c] = fmaf(hvu, alw[DHW + (size_t)c*HDIM + kb+u], acc[c]);
      }
    }
    const int row = s*BATCH + b;
    #pragma unroll
    for (int c=0;c<15;++c) out[OUT_POL + (size_t)row*NACT + c] = acc[c];
    out[OUT_BASE + row] = acc[15];
    double best = -1.0e300; int bi = 0;
    #pragma unroll
    for (int a2=0; a2<NACT; ++a2){
      const double v = (double)acc[a2] + gumbel_for((uint32_t)(row*NACT + a2));
      if (v > best){ best = v; bi = a2; }
    }
    out[OUT_ACT + row] = (float)bi;
  }
}

__global__ void finalize_kernel(const float* __restrict__ ws, float* __restrict__ out){
  int i = blockIdx.x*256 + threadIdx.x;
  if (i >= 2*HB) return;
  const int l = i / HB;
  const int r = i % HB;
  const int bq = r / HDIM;
  const int j  = r % HDIM;
  const float* hf = ws + (l==0 ? FH0 : FH1) + HB;   /* step-255 parity = 1 */
  const float* cf = ws + (l==0 ? FC0 : FC1);
  const size_t pidx = (size_t)(j>>2)*(BATCH*4) + bq*4 + (j&3);
  out[OUT_H + i] = hf[pidx];
  out[OUT_C + i] = cf[pidx];
}

extern "C" void kernel_launch(void* const* d_in, const int* in_sizes, int n_in,
                              void* d_out, int out_size, void* d_ws, size_t ws_size,
                              hipStream_t stream) {
  const float* obs     = (const float*)d_in[0];
  const int*   lastAct = (const int*)  d_in[1];
  const float* reward  = (const float*)d_in[2];
  const void*  term    =               d_in[3];
  const float* Wenc    = (const float*)d_in[4];
  const float* benc    = (const float*)d_in[5];
  const float* wih0    = (const float*)d_in[6];
  const float* whh0    = (const float*)d_in[7];
  const float* bih0    = (const float*)d_in[8];
  const float* bhh0    = (const float*)d_in[9];
  const float* wih1    = (const float*)d_in[10];
  const float* whh1    = (const float*)d_in[11];
  const float* bih1    = (const float*)d_in[12];
  const float* bhh1    = (const float*)d_in[13];
  const float* Wpol    = (const float*)d_in[14];
  const float* bpol    = (const float*)d_in[15];
  const float* Wbase   = (const float*)d_in[16];
  const float* bbase   = (const float*)d_in[17];
  float*  ws   = (float*)d_ws;
  int*    flag = (int*)(ws + OFF_FLAG);
  float*  alw  = (float*)((char*)d_ws + ALW_BYTES);
  float*  out  = (float*)d_out;

  /* zero h/c state (6*HB floats at FH0) every call */
  {
    const int nz = 6*HB;
    zero_kernel<<<(nz+255)/256, 256, 0, stream>>>(ws + FH0, nz);
  }
  detect_term_kernel<<<1, 256, 0, stream>>>(term, flag);
  nd_kernel<<<(TSTEPS*BATCH+255)/256, 256, 0, stream>>>(term, flag, ws + OFF_ND);
  prep_small_kernel<<<(DALW_N+255)/256, 256, 0, stream>>>(alw,
      bih0, bhh0, bih1, bhh1, benc, Wpol, bpol, Wbase, bbase);

  for (int t = -2; t <= 257; ++t) {
    step_kernel<<<594, 256, 0, stream>>>(
      obs, lastAct, reward,
      Wenc, wih0, whh0, wih1, whh1,
      ws, alw, out, t);
  }
  finalize_kernel<<<(2*HB+255)/256, 256, 0, stream>>>(ws, out);
}